// Round 11
// baseline (926.339 us; speedup 1.0000x reference)
//
#include <hip/hip_runtime.h>
#include <hip/hip_bf16.h>
#include <hip/hip_fp16.h>
#include <math.h>

constexpr int NE = 400000;
constexpr int NN = 40000;
constexpr int CD = 64;
constexpr int NGRAPH = 64;
constexpr int SCAN_BLOCKS = (NN + 255) / 256;   // 157

// ---------------- fc1: x0 = relu(x @ fc1_w + b) ----------------
__global__ void k_fc1(const float* __restrict__ x,
                      const float* __restrict__ w,
                      const float* __restrict__ b,
                      float* __restrict__ out) {
    int i = blockIdx.x * 256 + threadIdx.x;
    if (i >= NN * CD) return;
    int n = i >> 6, c = i & 63;
    float acc = b[c];
    #pragma unroll
    for (int k = 0; k < 9; ++k)
        acc = fmaf(x[n * 9 + k], w[k * 64 + c], acc);
    out[i] = fmaxf(acc, 0.f);
}

// ---------------- edge counts ----------------
__global__ void k_count(const int* __restrict__ ei, int* __restrict__ cnt) {
    int e = blockIdx.x * 256 + threadIdx.x;
    if (e >= NE) return;
    atomicAdd(&cnt[ei[e]], 1);
}

// ---------------- parallel scan, phase 1: per-block partial sums ----------------
__global__ void k_scan_part(const int* __restrict__ cnt, int* __restrict__ partials) {
    __shared__ int red[256];
    const int tid = threadIdx.x;
    const int i = blockIdx.x * 256 + tid;
    red[tid] = (i < NN) ? cnt[i] : 0;
    __syncthreads();
    for (int s = 128; s > 0; s >>= 1) {
        if (tid < s) red[tid] += red[tid + s];
        __syncthreads();
    }
    if (tid == 0) partials[blockIdx.x] = red[0];
}

// ---------------- phase 2: single-block scan of partials (nblk <= 256) ----------------
__global__ void k_scan_mid(const int* __restrict__ partials, int* __restrict__ offs, int nblk) {
    __shared__ int part[256];
    const int tid = threadIdx.x;
    const int v = (tid < nblk) ? partials[tid] : 0;
    part[tid] = v;
    __syncthreads();
    for (int off = 1; off < 256; off <<= 1) {
        int t = (tid >= off) ? part[tid - off] : 0;
        __syncthreads();
        part[tid] += t;
        __syncthreads();
    }
    if (tid < nblk) offs[tid] = part[tid] - v;   // exclusive
}

// ---------------- phase 3: in-block exclusive scan + base -> row_start, cursor ----------------
__global__ void k_scan_fill(const int* __restrict__ cnt, const int* __restrict__ offs,
                            int* __restrict__ row_start, int* __restrict__ cursor) {
    __shared__ int part[256];
    const int tid = threadIdx.x;
    const int i = blockIdx.x * 256 + tid;
    const int v = (i < NN) ? cnt[i] : 0;
    part[tid] = v;
    __syncthreads();
    for (int off = 1; off < 256; off <<= 1) {
        int t = (tid >= off) ? part[tid - off] : 0;
        __syncthreads();
        part[tid] += t;
        __syncthreads();
    }
    const int excl = part[tid] - v + offs[blockIdx.x];
    if (i < NN) { row_start[i] = excl; cursor[i] = excl; }
    if (i == NN - 1) row_start[NN] = NE;
}

// ---------------- scatter edge ids into CSR order ----------------
__global__ void k_scatter(const int* __restrict__ ei, int* __restrict__ cursor,
                          int* __restrict__ perm) {
    int e = blockIdx.x * 256 + threadIdx.x;
    if (e >= NE) return;
    int pos = atomicAdd(&cursor[ei[e]], 1);
    perm[pos] = e;
}

// ---------------- pre-gather col index + edge weights into CSR order ----------------
__global__ void k_edge_gather(const int* __restrict__ ei, const float* __restrict__ ew,
                              const int* __restrict__ perm,
                              int* __restrict__ colP, float* __restrict__ ewP) {
    int p = blockIdx.x * 256 + threadIdx.x;
    if (p >= NE) return;
    const int e = perm[p];
    colP[p] = ei[NE + e];
    ewP[3 * p]     = ew[3 * e];
    ewP[3 * p + 1] = ew[3 * e + 1];
    ewP[3 * p + 2] = ew[3 * e + 2];
}

// ---------------- node projection, split output:
// Pi[n][0:64]  = bf + x@Wf_top, Pi[n][64:128] = bs + x@Ws_top  (row-side, f32)
// Pj16[n][c] = half2(x@Wf_bot[c], x@Ws_bot[c])                 (col-side, gathered)
__global__ void k_proj(const float* __restrict__ x,
                       const float* __restrict__ wf, const float* __restrict__ bfp,
                       const float* __restrict__ wsp, const float* __restrict__ bsp,
                       float* __restrict__ Pi, __half2* __restrict__ Pj16) {
    __shared__ float xs[8][64];
    __shared__ float sS[8][64];
    const int tid = threadIdx.x;
    const int n0 = blockIdx.x * 8;
    for (int i = tid; i < 512; i += 256)
        xs[i >> 6][i & 63] = x[(size_t)(n0 + (i >> 6)) * 64 + (i & 63)];
    __syncthreads();
    const int q = tid >> 6, c = tid & 63;
    const float* __restrict__ wp = ((q & 2) ? wsp : wf) + ((q & 1) ? 64 * 64 : 0) + c;
    const float bias = (q == 0) ? bfp[c] : (q == 2 ? bsp[c] : 0.f);
    float acc[8];
    #pragma unroll
    for (int g = 0; g < 8; ++g) acc[g] = bias;
    for (int k = 0; k < 64; ++k) {
        const float wv = wp[k * 64];
        #pragma unroll
        for (int g = 0; g < 8; ++g) acc[g] = fmaf(xs[g][k], wv, acc[g]);
    }
    if (q == 3) {
        #pragma unroll
        for (int g = 0; g < 8; ++g) sS[g][c] = acc[g];
    }
    __syncthreads();
    #pragma unroll
    for (int g = 0; g < 8; ++g) {
        const size_t n = n0 + g;
        if (q == 0)      Pi[n * 128 + c]      = acc[g];
        else if (q == 2) Pi[n * 128 + 64 + c] = acc[g];
        else if (q == 1) Pj16[n * 64 + c]     = __floats2half2_rn(acc[g], sS[g][c]);
    }
}

// ---------------- CSR conv: 4 rows/wave, col 2-ahead / J 1-ahead pipeline ----------------
#define RPW 4
__global__ void k_edge_csr(const __half2* __restrict__ Pj,
                           const float* __restrict__ Pi,
                           const int* __restrict__ colP, const float* __restrict__ ewP,
                           const float* __restrict__ wfe, const float* __restrict__ wse,
                           const int* __restrict__ rs,
                           const float* __restrict__ xin, float* __restrict__ out) {
    const int c = threadIdx.x & 63;
    const int wv = (blockIdx.x * 256 + threadIdx.x) >> 6;
    const int r0 = wv * RPW;
    const float wf0 = wfe[c], wf1 = wfe[64 + c], wf2 = wfe[128 + c];
    const float ws0 = wse[c], ws1 = wse[64 + c], ws2 = wse[128 + c];
    int b[RPW], d[RPW], colN[RPW];
    float pf[RPW], ps[RPW], acc[RPW];
    float2 Jc[RPW], Jn[RPW];
    float E0c[RPW], E1c[RPW], E2c[RPW], E0n[RPW], E1n[RPW], E2n[RPW];
    #pragma unroll
    for (int k = 0; k < RPW; ++k) {
        const int r = r0 + k;
        b[k] = rs[r]; d[k] = rs[r + 1] - b[k];
        pf[k] = Pi[(size_t)r * 128 + c];
        ps[k] = Pi[(size_t)r * 128 + 64 + c];
        acc[k] = 0.f;
        Jc[k] = make_float2(0.f, 0.f); Jn[k] = make_float2(0.f, 0.f);
        E0c[k] = E1c[k] = E2c[k] = E0n[k] = E1n[k] = E2n[k] = 0.f;
        colN[k] = 0;
    }
    #pragma unroll
    for (int k = 0; k < RPW; ++k) {
        if (d[k] > 0) {
            const int col0 = colP[b[k]];
            Jc[k] = __half22float2(Pj[(size_t)col0 * 64 + c]);
            E0c[k] = ewP[3 * b[k]]; E1c[k] = ewP[3 * b[k] + 1]; E2c[k] = ewP[3 * b[k] + 2];
        }
        if (d[k] > 1) colN[k] = colP[b[k] + 1];
    }
    const int dmax = max(max(d[0], d[1]), max(d[2], d[3]));
    for (int i = 0; i < dmax; ++i) {
        #pragma unroll
        for (int k = 0; k < RPW; ++k) {
            if (i + 1 < d[k]) {
                Jn[k] = __half22float2(Pj[(size_t)colN[k] * 64 + c]);
                const int p = b[k] + i + 1;
                E0n[k] = ewP[3 * p]; E1n[k] = ewP[3 * p + 1]; E2n[k] = ewP[3 * p + 2];
            }
            if (i + 2 < d[k]) colN[k] = colP[b[k] + i + 2];
        }
        #pragma unroll
        for (int k = 0; k < RPW; ++k) {
            if (i < d[k]) {
                const float af = pf[k] + Jc[k].x + E0c[k] * wf0 + E1c[k] * wf1 + E2c[k] * wf2;
                const float as = ps[k] + Jc[k].y + E0c[k] * ws0 + E1c[k] * ws1 + E2c[k] * ws2;
                const float sg = 1.f / (1.f + __expf(-af));
                const float sp = (as > 20.f) ? as : __logf(1.f + __expf(as));
                acc[k] = fmaf(sg, sp, acc[k]);
            }
            Jc[k] = Jn[k];
            E0c[k] = E0n[k]; E1c[k] = E1n[k]; E2c[k] = E2n[k];
        }
    }
    #pragma unroll
    for (int k = 0; k < RPW; ++k) {
        const int r = r0 + k;
        out[(size_t)r * 64 + c] =
            fmaxf(fmaf(acc[k], 1.f / (float)max(d[k], 1), xin[(size_t)r * 64 + c]), 0.f);
    }
}

// ---------------- fused GRU: h = GRU(m, h), weights from L2 ----------------
__global__ void k_gru_fused(const float* __restrict__ m, float* __restrict__ h,
                            const float* __restrict__ wih, const float* __restrict__ bih,
                            const float* __restrict__ whh, const float* __restrict__ bhh) {
    __shared__ float ms[32 * 65], hs[32 * 65];
    const int tid = threadIdx.x;
    const int n0 = blockIdx.x * 32;
    for (int i = tid; i < 2048; i += 256) {
        ms[(i >> 6) * 65 + (i & 63)] = m[(size_t)n0 * 64 + i];
        hs[(i >> 6) * 65 + (i & 63)] = h[(size_t)n0 * 64 + i];
    }
    __syncthreads();
    const int c = tid & 63, tg = tid >> 6;
    float ir[8], iz[8], inn[8], hr[8], hz[8], hn[8];
    #pragma unroll
    for (int j = 0; j < 8; ++j) { ir[j]=0.f; iz[j]=0.f; inn[j]=0.f; hr[j]=0.f; hz[j]=0.f; hn[j]=0.f; }
    for (int k = 0; k < 64; ++k) {
        const float wir = wih[k * 192 + c];
        const float wiz = wih[k * 192 + 64 + c];
        const float win = wih[k * 192 + 128 + c];
        const float whr = whh[k * 192 + c];
        const float whz = whh[k * 192 + 64 + c];
        const float whn = whh[k * 192 + 128 + c];
        #pragma unroll
        for (int j = 0; j < 8; ++j) {
            const float mk = ms[(j * 4 + tg) * 65 + k];
            const float hk = hs[(j * 4 + tg) * 65 + k];
            ir[j]  = fmaf(mk, wir, ir[j]);
            iz[j]  = fmaf(mk, wiz, iz[j]);
            inn[j] = fmaf(mk, win, inn[j]);
            hr[j]  = fmaf(hk, whr, hr[j]);
            hz[j]  = fmaf(hk, whz, hz[j]);
            hn[j]  = fmaf(hk, whn, hn[j]);
        }
    }
    const float bir = bih[c], biz = bih[64 + c], bin = bih[128 + c];
    const float bhr = bhh[c], bhz = bhh[64 + c], bhn = bhh[128 + c];
    #pragma unroll
    for (int j = 0; j < 8; ++j) {
        const int n = n0 + j * 4 + tg;
        const float r  = 1.f / (1.f + __expf(-((ir[j] + bir) + (hr[j] + bhr))));
        const float zg = 1.f / (1.f + __expf(-((iz[j] + biz) + (hz[j] + bhz))));
        const float ng = tanhf((inn[j] + bin) + r * (hn[j] + bhn));
        h[(size_t)n * 64 + c] = (1.f - zg) * ng + zg * hs[(j * 4 + tg) * 65 + c];
    }
}

// ---------------- first-node-per-graph indices (searchsorted) ----------------
__global__ void k_idx(const int* __restrict__ batch, int* __restrict__ idx) {
    int g = threadIdx.x;
    if (g >= NGRAPH) return;
    int lo = 0, hi = NN;
    while (lo < hi) {
        int mid = (lo + hi) >> 1;
        if (batch[mid] < g) lo = mid + 1; else hi = mid;
    }
    idx[g] = lo;
}

// ---------------- readout head: all weights/activations in LDS ----------------
__global__ void k_head(const float* __restrict__ h, const int* __restrict__ idx,
                       const float* __restrict__ fcsw, const float* __restrict__ fcsb,
                       const float* __restrict__ f2cw, const float* __restrict__ f2cb,
                       const float* __restrict__ f3cw, const float* __restrict__ f3cb,
                       const float* __restrict__ f2dw, const float* __restrict__ f2db,
                       const float* __restrict__ f3dw, const float* __restrict__ f3db,
                       float* __restrict__ out) {
    __shared__ float hsB[4096];  // hsel -> xgs
    __shared__ float waB[4096];  // fcsw -> xcs
    __shared__ float wbB[4096];  // f2cw -> xds
    __shared__ float wcB[4096];  // f2dw -> f3 weights
    const int tid = threadIdx.x;
    for (int i = tid; i < 4096; i += 256) {
        int g = i >> 6, k = i & 63;
        hsB[i] = h[(size_t)idx[g] * 64 + k];
        waB[i] = fcsw[i];
        wbB[i] = f2cw[i];
        wcB[i] = f2dw[i];
    }
    __syncthreads();
    float v[16];
    #pragma unroll
    for (int j = 0; j < 16; ++j) {
        const int i = j * 256 + tid, g = i >> 6, c = i & 63;
        float a = fcsb[c];
        for (int k = 0; k < 64; ++k) a = fmaf(hsB[g * 64 + k], waB[k * 64 + c], a);
        v[j] = fmaxf(a, 0.f);
    }
    __syncthreads();
    #pragma unroll
    for (int j = 0; j < 16; ++j) hsB[j * 256 + tid] = v[j];   // xgs
    __syncthreads();
    float vc[16], vd[16];
    #pragma unroll
    for (int j = 0; j < 16; ++j) {
        const int i = j * 256 + tid, g = i >> 6, c = i & 63;
        float a1 = f2cb[c], a2 = f2db[c];
        for (int k = 0; k < 64; ++k) {
            const float xv = hsB[g * 64 + k];
            a1 = fmaf(xv, wbB[k * 64 + c], a1);
            a2 = fmaf(xv, wcB[k * 64 + c], a2);
        }
        vc[j] = fmaxf(a1, 0.f);
        vd[j] = fmaxf(a2, 0.f);
    }
    __syncthreads();
    #pragma unroll
    for (int j = 0; j < 16; ++j) {
        waB[j * 256 + tid] = vc[j];   // xcs
        wbB[j * 256 + tid] = vd[j];   // xds
    }
    if (tid < 128) wcB[tid] = f3cw[tid];
    else           wcB[tid] = f3dw[tid - 128];
    __syncthreads();
    if (tid < 128) {
        int g = tid >> 1, j = tid & 1;
        float a = f3cb[j];
        for (int k = 0; k < 64; ++k) a = fmaf(waB[g * 64 + k], wcB[k * 2 + j], a);
        out[g * 2 + j] = 1.f / (1.f + expf(-a));
    } else {
        int t = tid - 128, g = t >> 1, j = t & 1;
        float a = f3db[j];
        for (int k = 0; k < 64; ++k) a = fmaf(wbB[g * 64 + k], wcB[128 + k * 2 + j], a);
        out[128 + g * 2 + j] = a;
    }
}

// ---------------- host launcher ----------------
extern "C" void kernel_launch(void* const* d_in, const int* in_sizes, int n_in,
                              void* d_out, int out_size, void* d_ws, size_t ws_size,
                              hipStream_t stream) {
    (void)in_sizes; (void)n_in; (void)out_size; (void)ws_size;
    const float* x    = (const float*)d_in[0];
    const int* ei1    = (const int*)d_in[1];
    const int* ei2    = (const int*)d_in[2];
    const float* w1   = (const float*)d_in[3];
    const float* w2   = (const float*)d_in[4];
    const int* batch  = (const int*)d_in[5];
    const float* fc1w = (const float*)d_in[6];
    const float* fc1b = (const float*)d_in[7];
    const float* lfw  = (const float*)d_in[8];
    const float* lfb  = (const float*)d_in[9];
    const float* lsw  = (const float*)d_in[10];
    const float* lsb  = (const float*)d_in[11];
    const float* wih  = (const float*)d_in[12];
    const float* bih  = (const float*)d_in[13];
    const float* whh  = (const float*)d_in[14];
    const float* bhh  = (const float*)d_in[15];
    const float* fcsw = (const float*)d_in[16];
    const float* fcsb = (const float*)d_in[17];
    const float* f2cw = (const float*)d_in[18];
    const float* f2cb = (const float*)d_in[19];
    const float* f3cw = (const float*)d_in[20];
    const float* f3cb = (const float*)d_in[21];
    const float* f2dw = (const float*)d_in[22];
    const float* f2db = (const float*)d_in[23];
    const float* f3dw = (const float*)d_in[24];
    const float* f3db = (const float*)d_in[25];

    char* ws = (char*)d_ws;
    size_t off = 0;
    auto alloc = [&](size_t bytes) { char* p = ws + off; off += (bytes + 255) & ~size_t(255); return p; };
    float*   Pi    = (float*)alloc(size_t(NN) * 128 * 4);      // 20.5 MB
    __half2* Pj16  = (__half2*)alloc(size_t(NN) * 64 * 4);     // 10.2 MB
    float*   hbuf  = (float*)alloc(size_t(NN) * CD * 4);
    float*   mbuf  = (float*)alloc(size_t(NN) * CD * 4);
    int*   cnt1  = (int*)alloc(size_t(NN) * 4);
    int*   cnt2  = (int*)alloc(size_t(NN) * 4);
    int*   rs1   = (int*)alloc(size_t(NN + 1) * 4);
    int*   rs2   = (int*)alloc(size_t(NN + 1) * 4);
    int*   cur1  = (int*)alloc(size_t(NN + 1) * 4);
    int*   cur2  = (int*)alloc(size_t(NN + 1) * 4);
    int*   perm1 = (int*)alloc(size_t(NE) * 4);
    int*   perm2 = (int*)alloc(size_t(NE) * 4);
    int*   colP1 = (int*)alloc(size_t(NE) * 4);
    int*   colP2 = (int*)alloc(size_t(NE) * 4);
    float* ewP1  = (float*)alloc(size_t(NE) * 12);
    float* ewP2  = (float*)alloc(size_t(NE) * 12);
    int*   part1 = (int*)alloc(256 * 4);
    int*   part2 = (int*)alloc(256 * 4);
    int*   offs1 = (int*)alloc(256 * 4);
    int*   offs2 = (int*)alloc(256 * 4);
    int*   idx   = (int*)alloc(256);

    const int NB_NC = (NN * CD + 255) / 256;
    const int NB_E  = (NE + 255) / 256;
    const int EDGE_BLOCKS = NN / (RPW * 4);   // 2500: 4 waves/block, 4 rows/wave
    const int PROJ_BLOCKS = NN / 8;           // 5000
    const int GRU_BLOCKS  = NN / 32;          // 1250

    const float* lfe = lfw + 128 * 64;
    const float* lse = lsw + 128 * 64;

    // CSR build (parallel scan) + edge pre-gather
    hipMemsetAsync(cnt1, 0, size_t(NN) * 4, stream);
    hipMemsetAsync(cnt2, 0, size_t(NN) * 4, stream);
    k_count<<<NB_E, 256, 0, stream>>>(ei1, cnt1);
    k_count<<<NB_E, 256, 0, stream>>>(ei2, cnt2);
    k_scan_part<<<SCAN_BLOCKS, 256, 0, stream>>>(cnt1, part1);
    k_scan_part<<<SCAN_BLOCKS, 256, 0, stream>>>(cnt2, part2);
    k_scan_mid<<<1, 256, 0, stream>>>(part1, offs1, SCAN_BLOCKS);
    k_scan_mid<<<1, 256, 0, stream>>>(part2, offs2, SCAN_BLOCKS);
    k_scan_fill<<<SCAN_BLOCKS, 256, 0, stream>>>(cnt1, offs1, rs1, cur1);
    k_scan_fill<<<SCAN_BLOCKS, 256, 0, stream>>>(cnt2, offs2, rs2, cur2);
    k_scatter<<<NB_E, 256, 0, stream>>>(ei1, cur1, perm1);
    k_scatter<<<NB_E, 256, 0, stream>>>(ei2, cur2, perm2);
    k_edge_gather<<<NB_E, 256, 0, stream>>>(ei1, w1, perm1, colP1, ewP1);
    k_edge_gather<<<NB_E, 256, 0, stream>>>(ei2, w2, perm2, colP2, ewP2);

    k_fc1<<<NB_NC, 256, 0, stream>>>(x, fc1w, fc1b, hbuf);

    for (int it = 0; it < 3; ++it) {
        k_proj<<<PROJ_BLOCKS, 256, 0, stream>>>(hbuf, lfw, lfb, lsw, lsb, Pi, Pj16);
        k_edge_csr<<<EDGE_BLOCKS, 256, 0, stream>>>(Pj16, Pi, colP2, ewP2,
                                                    lfe, lse, rs2, hbuf, mbuf);
        k_proj<<<PROJ_BLOCKS, 256, 0, stream>>>(mbuf, lfw, lfb, lsw, lsb, Pi, Pj16);
        k_edge_csr<<<EDGE_BLOCKS, 256, 0, stream>>>(Pj16, Pi, colP1, ewP1,
                                                    lfe, lse, rs1, mbuf, mbuf);
        k_gru_fused<<<GRU_BLOCKS, 256, 0, stream>>>(mbuf, hbuf, wih, bih, whh, bhh);
    }

    k_idx<<<1, 64, 0, stream>>>(batch, idx);
    k_head<<<1, 256, 0, stream>>>(hbuf, idx, fcsw, fcsb, f2cw, f2cb, f3cw, f3cb,
                                  f2dw, f2db, f3dw, f3db, (float*)d_out);
}

// Round 12
// 777.172 us; speedup vs baseline: 1.1919x; 1.1919x over previous
//
#include <hip/hip_runtime.h>
#include <hip/hip_bf16.h>
#include <hip/hip_fp16.h>
#include <math.h>

constexpr int NE = 400000;
constexpr int NN = 40000;
constexpr int CD = 64;
constexpr int NGRAPH = 64;
constexpr int SCAN_BLOCKS = (NN + 255) / 256;   // 157

// ---------------- fc1: x0 = relu(x @ fc1_w + b) ----------------
__global__ void k_fc1(const float* __restrict__ x,
                      const float* __restrict__ w,
                      const float* __restrict__ b,
                      float* __restrict__ out) {
    int i = blockIdx.x * 256 + threadIdx.x;
    if (i >= NN * CD) return;
    int n = i >> 6, c = i & 63;
    float acc = b[c];
    #pragma unroll
    for (int k = 0; k < 9; ++k)
        acc = fmaf(x[n * 9 + k], w[k * 64 + c], acc);
    out[i] = fmaxf(acc, 0.f);
}

// ---------------- edge counts ----------------
__global__ void k_count(const int* __restrict__ ei, int* __restrict__ cnt) {
    int e = blockIdx.x * 256 + threadIdx.x;
    if (e >= NE) return;
    atomicAdd(&cnt[ei[e]], 1);
}

// ---------------- parallel scan, phase 1: per-block partial sums ----------------
__global__ void k_scan_part(const int* __restrict__ cnt, int* __restrict__ partials) {
    __shared__ int red[256];
    const int tid = threadIdx.x;
    const int i = blockIdx.x * 256 + tid;
    red[tid] = (i < NN) ? cnt[i] : 0;
    __syncthreads();
    for (int s = 128; s > 0; s >>= 1) {
        if (tid < s) red[tid] += red[tid + s];
        __syncthreads();
    }
    if (tid == 0) partials[blockIdx.x] = red[0];
}

// ---------------- phase 2: single-block scan of partials (nblk <= 256) ----------------
__global__ void k_scan_mid(const int* __restrict__ partials, int* __restrict__ offs, int nblk) {
    __shared__ int part[256];
    const int tid = threadIdx.x;
    const int v = (tid < nblk) ? partials[tid] : 0;
    part[tid] = v;
    __syncthreads();
    for (int off = 1; off < 256; off <<= 1) {
        int t = (tid >= off) ? part[tid - off] : 0;
        __syncthreads();
        part[tid] += t;
        __syncthreads();
    }
    if (tid < nblk) offs[tid] = part[tid] - v;   // exclusive
}

// ---------------- phase 3: in-block exclusive scan + base -> row_start, cursor ----------------
__global__ void k_scan_fill(const int* __restrict__ cnt, const int* __restrict__ offs,
                            int* __restrict__ row_start, int* __restrict__ cursor) {
    __shared__ int part[256];
    const int tid = threadIdx.x;
    const int i = blockIdx.x * 256 + tid;
    const int v = (i < NN) ? cnt[i] : 0;
    part[tid] = v;
    __syncthreads();
    for (int off = 1; off < 256; off <<= 1) {
        int t = (tid >= off) ? part[tid - off] : 0;
        __syncthreads();
        part[tid] += t;
        __syncthreads();
    }
    const int excl = part[tid] - v + offs[blockIdx.x];
    if (i < NN) { row_start[i] = excl; cursor[i] = excl; }
    if (i == NN - 1) row_start[NN] = NE;
}

// ---------------- scatter edge ids into CSR order ----------------
__global__ void k_scatter(const int* __restrict__ ei, int* __restrict__ cursor,
                          int* __restrict__ perm) {
    int e = blockIdx.x * 256 + threadIdx.x;
    if (e >= NE) return;
    int pos = atomicAdd(&cursor[ei[e]], 1);
    perm[pos] = e;
}

// ---------------- pre-gather row/col/edge-weights into CSR order ----------------
__global__ void k_edge_gather(const int* __restrict__ ei, const float* __restrict__ ew,
                              const int* __restrict__ perm,
                              int* __restrict__ rowP, int* __restrict__ colP,
                              float* __restrict__ ewP) {
    int p = blockIdx.x * 256 + threadIdx.x;
    if (p >= NE) return;
    const int e = perm[p];
    rowP[p] = ei[e];
    colP[p] = ei[NE + e];
    ewP[3 * p]     = ew[3 * e];
    ewP[3 * p + 1] = ew[3 * e + 1];
    ewP[3 * p + 2] = ew[3 * e + 2];
}

// ---------------- node projection, split output:
// Pi[n][0:64]  = bf + x@Wf_top, Pi[n][64:128] = bs + x@Ws_top  (row-side, f32)
// Pj16[n][c] = half2(x@Wf_bot[c], x@Ws_bot[c])                 (col-side, gathered)
__global__ void k_proj(const float* __restrict__ x,
                       const float* __restrict__ wf, const float* __restrict__ bfp,
                       const float* __restrict__ wsp, const float* __restrict__ bsp,
                       float* __restrict__ Pi, __half2* __restrict__ Pj16) {
    __shared__ float xs[8][64];
    __shared__ float sS[8][64];
    const int tid = threadIdx.x;
    const int n0 = blockIdx.x * 8;
    for (int i = tid; i < 512; i += 256)
        xs[i >> 6][i & 63] = x[(size_t)(n0 + (i >> 6)) * 64 + (i & 63)];
    __syncthreads();
    const int q = tid >> 6, c = tid & 63;
    const float* __restrict__ wp = ((q & 2) ? wsp : wf) + ((q & 1) ? 64 * 64 : 0) + c;
    const float bias = (q == 0) ? bfp[c] : (q == 2 ? bsp[c] : 0.f);
    float acc[8];
    #pragma unroll
    for (int g = 0; g < 8; ++g) acc[g] = bias;
    for (int k = 0; k < 64; ++k) {
        const float wv = wp[k * 64];
        #pragma unroll
        for (int g = 0; g < 8; ++g) acc[g] = fmaf(xs[g][k], wv, acc[g]);
    }
    if (q == 3) {
        #pragma unroll
        for (int g = 0; g < 8; ++g) sS[g][c] = acc[g];
    }
    __syncthreads();
    #pragma unroll
    for (int g = 0; g < 8; ++g) {
        const size_t n = n0 + g;
        if (q == 0)      Pi[n * 128 + c]      = acc[g];
        else if (q == 2) Pi[n * 128 + 64 + c] = acc[g];
        else if (q == 1) Pj16[n * 64 + c]     = __floats2half2_rn(acc[g], sS[g][c]);
    }
}

// ---------------- edge-parallel row-range conv: 16 rows/block, wave=edge ----------------
__launch_bounds__(256, 4)
__global__ void k_edge_range(const __half2* __restrict__ Pj,
                             const float* __restrict__ Pi,
                             const int* __restrict__ rowP, const int* __restrict__ colP,
                             const float* __restrict__ ewP,
                             const float* __restrict__ wfe, const float* __restrict__ wse,
                             const int* __restrict__ rs,
                             const float* __restrict__ xin, float* __restrict__ out) {
    __shared__ float piS[16][128];        // staged row-side projections
    __shared__ float accS[4][16][64];     // per-wave accumulators
    __shared__ int rsS[17];
    const int tid = threadIdx.x;
    const int c = tid & 63, wv = tid >> 6;
    const int r0 = blockIdx.x * 16;
    for (int i = tid; i < 2048; i += 256)
        piS[i >> 7][i & 127] = Pi[(size_t)r0 * 128 + i];
    for (int i = tid; i < 4096; i += 256)
        ((float*)accS)[i] = 0.f;
    if (tid < 17) rsS[tid] = rs[r0 + tid];
    __syncthreads();
    const float wf0 = wfe[c], wf1 = wfe[64 + c], wf2 = wfe[128 + c];
    const float ws0 = wse[c], ws1 = wse[64 + c], ws2 = wse[128 + c];
    const int pbeg = rsS[0], pend = rsS[16];
    #pragma unroll 2
    for (int p = pbeg + wv; p < pend; p += 4) {
        const int row = rowP[p] - r0;
        const int col = colP[p];
        const float e0 = ewP[3 * p], e1 = ewP[3 * p + 1], e2 = ewP[3 * p + 2];
        const float2 J = __half22float2(Pj[(size_t)col * 64 + c]);
        const float af = piS[row][c]      + J.x + e0 * wf0 + e1 * wf1 + e2 * wf2;
        const float as = piS[row][64 + c] + J.y + e0 * ws0 + e1 * ws1 + e2 * ws2;
        const float sg = 1.f / (1.f + __expf(-af));
        const float sp = (as > 20.f) ? as : __logf(1.f + __expf(as));
        accS[wv][row][c] += sg * sp;
    }
    __syncthreads();
    for (int i = tid; i < 1024; i += 256) {
        const int row = i >> 6, ch = i & 63;
        const float s = accS[0][row][ch] + accS[1][row][ch]
                      + accS[2][row][ch] + accS[3][row][ch];
        const int deg = rsS[row + 1] - rsS[row];
        const size_t o = (size_t)(r0 + row) * 64 + ch;
        out[o] = fmaxf(fmaf(s, 1.f / (float)max(deg, 1), xin[o]), 0.f);
    }
}

// ---------------- fused GRU: h = GRU(m, h), weights from L2 ----------------
__global__ void k_gru_fused(const float* __restrict__ m, float* __restrict__ h,
                            const float* __restrict__ wih, const float* __restrict__ bih,
                            const float* __restrict__ whh, const float* __restrict__ bhh) {
    __shared__ float ms[32 * 65], hs[32 * 65];
    const int tid = threadIdx.x;
    const int n0 = blockIdx.x * 32;
    for (int i = tid; i < 2048; i += 256) {
        ms[(i >> 6) * 65 + (i & 63)] = m[(size_t)n0 * 64 + i];
        hs[(i >> 6) * 65 + (i & 63)] = h[(size_t)n0 * 64 + i];
    }
    __syncthreads();
    const int c = tid & 63, tg = tid >> 6;
    float ir[8], iz[8], inn[8], hr[8], hz[8], hn[8];
    #pragma unroll
    for (int j = 0; j < 8; ++j) { ir[j]=0.f; iz[j]=0.f; inn[j]=0.f; hr[j]=0.f; hz[j]=0.f; hn[j]=0.f; }
    for (int k = 0; k < 64; ++k) {
        const float wir = wih[k * 192 + c];
        const float wiz = wih[k * 192 + 64 + c];
        const float win = wih[k * 192 + 128 + c];
        const float whr = whh[k * 192 + c];
        const float whz = whh[k * 192 + 64 + c];
        const float whn = whh[k * 192 + 128 + c];
        #pragma unroll
        for (int j = 0; j < 8; ++j) {
            const float mk = ms[(j * 4 + tg) * 65 + k];
            const float hk = hs[(j * 4 + tg) * 65 + k];
            ir[j]  = fmaf(mk, wir, ir[j]);
            iz[j]  = fmaf(mk, wiz, iz[j]);
            inn[j] = fmaf(mk, win, inn[j]);
            hr[j]  = fmaf(hk, whr, hr[j]);
            hz[j]  = fmaf(hk, whz, hz[j]);
            hn[j]  = fmaf(hk, whn, hn[j]);
        }
    }
    const float bir = bih[c], biz = bih[64 + c], bin = bih[128 + c];
    const float bhr = bhh[c], bhz = bhh[64 + c], bhn = bhh[128 + c];
    #pragma unroll
    for (int j = 0; j < 8; ++j) {
        const int n = n0 + j * 4 + tg;
        const float r  = 1.f / (1.f + __expf(-((ir[j] + bir) + (hr[j] + bhr))));
        const float zg = 1.f / (1.f + __expf(-((iz[j] + biz) + (hz[j] + bhz))));
        const float ng = tanhf((inn[j] + bin) + r * (hn[j] + bhn));
        h[(size_t)n * 64 + c] = (1.f - zg) * ng + zg * hs[(j * 4 + tg) * 65 + c];
    }
}

// ---------------- first-node-per-graph indices (searchsorted) ----------------
__global__ void k_idx(const int* __restrict__ batch, int* __restrict__ idx) {
    int g = threadIdx.x;
    if (g >= NGRAPH) return;
    int lo = 0, hi = NN;
    while (lo < hi) {
        int mid = (lo + hi) >> 1;
        if (batch[mid] < g) lo = mid + 1; else hi = mid;
    }
    idx[g] = lo;
}

// ---------------- readout head: all weights/activations in LDS ----------------
__global__ void k_head(const float* __restrict__ h, const int* __restrict__ idx,
                       const float* __restrict__ fcsw, const float* __restrict__ fcsb,
                       const float* __restrict__ f2cw, const float* __restrict__ f2cb,
                       const float* __restrict__ f3cw, const float* __restrict__ f3cb,
                       const float* __restrict__ f2dw, const float* __restrict__ f2db,
                       const float* __restrict__ f3dw, const float* __restrict__ f3db,
                       float* __restrict__ out) {
    __shared__ float hsB[4096];  // hsel -> xgs
    __shared__ float waB[4096];  // fcsw -> xcs
    __shared__ float wbB[4096];  // f2cw -> xds
    __shared__ float wcB[4096];  // f2dw -> f3 weights
    const int tid = threadIdx.x;
    for (int i = tid; i < 4096; i += 256) {
        int g = i >> 6, k = i & 63;
        hsB[i] = h[(size_t)idx[g] * 64 + k];
        waB[i] = fcsw[i];
        wbB[i] = f2cw[i];
        wcB[i] = f2dw[i];
    }
    __syncthreads();
    float v[16];
    #pragma unroll
    for (int j = 0; j < 16; ++j) {
        const int i = j * 256 + tid, g = i >> 6, c = i & 63;
        float a = fcsb[c];
        for (int k = 0; k < 64; ++k) a = fmaf(hsB[g * 64 + k], waB[k * 64 + c], a);
        v[j] = fmaxf(a, 0.f);
    }
    __syncthreads();
    #pragma unroll
    for (int j = 0; j < 16; ++j) hsB[j * 256 + tid] = v[j];   // xgs
    __syncthreads();
    float vc[16], vd[16];
    #pragma unroll
    for (int j = 0; j < 16; ++j) {
        const int i = j * 256 + tid, g = i >> 6, c = i & 63;
        float a1 = f2cb[c], a2 = f2db[c];
        for (int k = 0; k < 64; ++k) {
            const float xv = hsB[g * 64 + k];
            a1 = fmaf(xv, wbB[k * 64 + c], a1);
            a2 = fmaf(xv, wcB[k * 64 + c], a2);
        }
        vc[j] = fmaxf(a1, 0.f);
        vd[j] = fmaxf(a2, 0.f);
    }
    __syncthreads();
    #pragma unroll
    for (int j = 0; j < 16; ++j) {
        waB[j * 256 + tid] = vc[j];   // xcs
        wbB[j * 256 + tid] = vd[j];   // xds
    }
    if (tid < 128) wcB[tid] = f3cw[tid];
    else           wcB[tid] = f3dw[tid - 128];
    __syncthreads();
    if (tid < 128) {
        int g = tid >> 1, j = tid & 1;
        float a = f3cb[j];
        for (int k = 0; k < 64; ++k) a = fmaf(waB[g * 64 + k], wcB[k * 2 + j], a);
        out[g * 2 + j] = 1.f / (1.f + expf(-a));
    } else {
        int t = tid - 128, g = t >> 1, j = t & 1;
        float a = f3db[j];
        for (int k = 0; k < 64; ++k) a = fmaf(wbB[g * 64 + k], wcB[128 + k * 2 + j], a);
        out[128 + g * 2 + j] = a;
    }
}

// ---------------- host launcher ----------------
extern "C" void kernel_launch(void* const* d_in, const int* in_sizes, int n_in,
                              void* d_out, int out_size, void* d_ws, size_t ws_size,
                              hipStream_t stream) {
    (void)in_sizes; (void)n_in; (void)out_size; (void)ws_size;
    const float* x    = (const float*)d_in[0];
    const int* ei1    = (const int*)d_in[1];
    const int* ei2    = (const int*)d_in[2];
    const float* w1   = (const float*)d_in[3];
    const float* w2   = (const float*)d_in[4];
    const int* batch  = (const int*)d_in[5];
    const float* fc1w = (const float*)d_in[6];
    const float* fc1b = (const float*)d_in[7];
    const float* lfw  = (const float*)d_in[8];
    const float* lfb  = (const float*)d_in[9];
    const float* lsw  = (const float*)d_in[10];
    const float* lsb  = (const float*)d_in[11];
    const float* wih  = (const float*)d_in[12];
    const float* bih  = (const float*)d_in[13];
    const float* whh  = (const float*)d_in[14];
    const float* bhh  = (const float*)d_in[15];
    const float* fcsw = (const float*)d_in[16];
    const float* fcsb = (const float*)d_in[17];
    const float* f2cw = (const float*)d_in[18];
    const float* f2cb = (const float*)d_in[19];
    const float* f3cw = (const float*)d_in[20];
    const float* f3cb = (const float*)d_in[21];
    const float* f2dw = (const float*)d_in[22];
    const float* f2db = (const float*)d_in[23];
    const float* f3dw = (const float*)d_in[24];
    const float* f3db = (const float*)d_in[25];

    char* ws = (char*)d_ws;
    size_t off = 0;
    auto alloc = [&](size_t bytes) { char* p = ws + off; off += (bytes + 255) & ~size_t(255); return p; };
    float*   Pi    = (float*)alloc(size_t(NN) * 128 * 4);      // 20.5 MB
    __half2* Pj16  = (__half2*)alloc(size_t(NN) * 64 * 4);     // 10.2 MB
    float*   hbuf  = (float*)alloc(size_t(NN) * CD * 4);
    float*   mbuf  = (float*)alloc(size_t(NN) * CD * 4);
    int*   cnt1  = (int*)alloc(size_t(NN) * 4);
    int*   cnt2  = (int*)alloc(size_t(NN) * 4);
    int*   rs1   = (int*)alloc(size_t(NN + 1) * 4);
    int*   rs2   = (int*)alloc(size_t(NN + 1) * 4);
    int*   cur1  = (int*)alloc(size_t(NN + 1) * 4);
    int*   cur2  = (int*)alloc(size_t(NN + 1) * 4);
    int*   perm1 = (int*)alloc(size_t(NE) * 4);
    int*   perm2 = (int*)alloc(size_t(NE) * 4);
    int*   rowP1 = (int*)alloc(size_t(NE) * 4);
    int*   rowP2 = (int*)alloc(size_t(NE) * 4);
    int*   colP1 = (int*)alloc(size_t(NE) * 4);
    int*   colP2 = (int*)alloc(size_t(NE) * 4);
    float* ewP1  = (float*)alloc(size_t(NE) * 12);
    float* ewP2  = (float*)alloc(size_t(NE) * 12);
    int*   part1 = (int*)alloc(256 * 4);
    int*   part2 = (int*)alloc(256 * 4);
    int*   offs1 = (int*)alloc(256 * 4);
    int*   offs2 = (int*)alloc(256 * 4);
    int*   idx   = (int*)alloc(256);

    const int NB_NC = (NN * CD + 255) / 256;
    const int NB_E  = (NE + 255) / 256;
    const int EDGE_BLOCKS = NN / 16;   // 2500 row-range blocks
    const int PROJ_BLOCKS = NN / 8;    // 5000
    const int GRU_BLOCKS  = NN / 32;   // 1250

    const float* lfe = lfw + 128 * 64;
    const float* lse = lsw + 128 * 64;

    // CSR build (parallel scan) + edge pre-gather
    hipMemsetAsync(cnt1, 0, size_t(NN) * 4, stream);
    hipMemsetAsync(cnt2, 0, size_t(NN) * 4, stream);
    k_count<<<NB_E, 256, 0, stream>>>(ei1, cnt1);
    k_count<<<NB_E, 256, 0, stream>>>(ei2, cnt2);
    k_scan_part<<<SCAN_BLOCKS, 256, 0, stream>>>(cnt1, part1);
    k_scan_part<<<SCAN_BLOCKS, 256, 0, stream>>>(cnt2, part2);
    k_scan_mid<<<1, 256, 0, stream>>>(part1, offs1, SCAN_BLOCKS);
    k_scan_mid<<<1, 256, 0, stream>>>(part2, offs2, SCAN_BLOCKS);
    k_scan_fill<<<SCAN_BLOCKS, 256, 0, stream>>>(cnt1, offs1, rs1, cur1);
    k_scan_fill<<<SCAN_BLOCKS, 256, 0, stream>>>(cnt2, offs2, rs2, cur2);
    k_scatter<<<NB_E, 256, 0, stream>>>(ei1, cur1, perm1);
    k_scatter<<<NB_E, 256, 0, stream>>>(ei2, cur2, perm2);
    k_edge_gather<<<NB_E, 256, 0, stream>>>(ei1, w1, perm1, rowP1, colP1, ewP1);
    k_edge_gather<<<NB_E, 256, 0, stream>>>(ei2, w2, perm2, rowP2, colP2, ewP2);

    k_fc1<<<NB_NC, 256, 0, stream>>>(x, fc1w, fc1b, hbuf);

    for (int it = 0; it < 3; ++it) {
        k_proj<<<PROJ_BLOCKS, 256, 0, stream>>>(hbuf, lfw, lfb, lsw, lsb, Pi, Pj16);
        k_edge_range<<<EDGE_BLOCKS, 256, 0, stream>>>(Pj16, Pi, rowP2, colP2, ewP2,
                                                      lfe, lse, rs2, hbuf, mbuf);
        k_proj<<<PROJ_BLOCKS, 256, 0, stream>>>(mbuf, lfw, lfb, lsw, lsb, Pi, Pj16);
        k_edge_range<<<EDGE_BLOCKS, 256, 0, stream>>>(Pj16, Pi, rowP1, colP1, ewP1,
                                                      lfe, lse, rs1, mbuf, mbuf);
        k_gru_fused<<<GRU_BLOCKS, 256, 0, stream>>>(mbuf, hbuf, wih, bih, whh, bhh);
    }

    k_idx<<<1, 64, 0, stream>>>(batch, idx);
    k_head<<<1, 256, 0, stream>>>(hbuf, idx, fcsw, fcsb, f2cw, f2cb, f3cw, f3cb,
                                  f2dw, f2db, f3dw, f3db, (float*)d_out);
}

// Round 13
// 739.251 us; speedup vs baseline: 1.2531x; 1.0513x over previous
//
#include <hip/hip_runtime.h>
#include <hip/hip_bf16.h>
#include <hip/hip_fp16.h>
#include <math.h>

constexpr int NE = 400000;
constexpr int NN = 40000;
constexpr int CD = 64;
constexpr int NGRAPH = 64;
constexpr int SCAN_BLOCKS = (NN + 255) / 256;   // 157

// ---------------- fc1: x0 = relu(x @ fc1_w + b) ----------------
__global__ void k_fc1(const float* __restrict__ x,
                      const float* __restrict__ w,
                      const float* __restrict__ b,
                      float* __restrict__ out) {
    int i = blockIdx.x * 256 + threadIdx.x;
    if (i >= NN * CD) return;
    int n = i >> 6, c = i & 63;
    float acc = b[c];
    #pragma unroll
    for (int k = 0; k < 9; ++k)
        acc = fmaf(x[n * 9 + k], w[k * 64 + c], acc);
    out[i] = fmaxf(acc, 0.f);
}

// ---------------- edge counts ----------------
__global__ void k_count(const int* __restrict__ ei, int* __restrict__ cnt) {
    int e = blockIdx.x * 256 + threadIdx.x;
    if (e >= NE) return;
    atomicAdd(&cnt[ei[e]], 1);
}

// ---------------- parallel scan, phase 1: per-block partial sums ----------------
__global__ void k_scan_part(const int* __restrict__ cnt, int* __restrict__ partials) {
    __shared__ int red[256];
    const int tid = threadIdx.x;
    const int i = blockIdx.x * 256 + tid;
    red[tid] = (i < NN) ? cnt[i] : 0;
    __syncthreads();
    for (int s = 128; s > 0; s >>= 1) {
        if (tid < s) red[tid] += red[tid + s];
        __syncthreads();
    }
    if (tid == 0) partials[blockIdx.x] = red[0];
}

// ---------------- phase 2: single-block scan of partials (nblk <= 256) ----------------
__global__ void k_scan_mid(const int* __restrict__ partials, int* __restrict__ offs, int nblk) {
    __shared__ int part[256];
    const int tid = threadIdx.x;
    const int v = (tid < nblk) ? partials[tid] : 0;
    part[tid] = v;
    __syncthreads();
    for (int off = 1; off < 256; off <<= 1) {
        int t = (tid >= off) ? part[tid - off] : 0;
        __syncthreads();
        part[tid] += t;
        __syncthreads();
    }
    if (tid < nblk) offs[tid] = part[tid] - v;   // exclusive
}

// ---------------- phase 3: in-block exclusive scan + base -> row_start, cursor ----------------
__global__ void k_scan_fill(const int* __restrict__ cnt, const int* __restrict__ offs,
                            int* __restrict__ row_start, int* __restrict__ cursor) {
    __shared__ int part[256];
    const int tid = threadIdx.x;
    const int i = blockIdx.x * 256 + tid;
    const int v = (i < NN) ? cnt[i] : 0;
    part[tid] = v;
    __syncthreads();
    for (int off = 1; off < 256; off <<= 1) {
        int t = (tid >= off) ? part[tid - off] : 0;
        __syncthreads();
        part[tid] += t;
        __syncthreads();
    }
    const int excl = part[tid] - v + offs[blockIdx.x];
    if (i < NN) { row_start[i] = excl; cursor[i] = excl; }
    if (i == NN - 1) row_start[NN] = NE;
}

// ---------------- scatter edge ids into CSR order ----------------
__global__ void k_scatter(const int* __restrict__ ei, int* __restrict__ cursor,
                          int* __restrict__ perm) {
    int e = blockIdx.x * 256 + threadIdx.x;
    if (e >= NE) return;
    int pos = atomicAdd(&cursor[ei[e]], 1);
    perm[pos] = e;
}

// ---------------- pre-gather packed edge data into CSR order ----------------
__global__ void k_edge_gather(const int* __restrict__ ei, const float* __restrict__ ew,
                              const int* __restrict__ perm,
                              int2* __restrict__ rcP, float4* __restrict__ ewP) {
    int p = blockIdx.x * 256 + threadIdx.x;
    if (p >= NE) return;
    const int e = perm[p];
    rcP[p] = make_int2(ei[e], ei[NE + e]);
    ewP[p] = make_float4(ew[3 * e], ew[3 * e + 1], ew[3 * e + 2], 0.f);
}

// ---------------- node projection, split output:
// Pi[n][0:64]  = bf + x@Wf_top, Pi[n][64:128] = bs + x@Ws_top  (row-side, f32)
// Pj16[n][c] = half2(x@Wf_bot[c], x@Ws_bot[c])                 (col-side, gathered)
__global__ void k_proj(const float* __restrict__ x,
                       const float* __restrict__ wf, const float* __restrict__ bfp,
                       const float* __restrict__ wsp, const float* __restrict__ bsp,
                       float* __restrict__ Pi, __half2* __restrict__ Pj16) {
    __shared__ float xs[8][64];
    __shared__ float sS[8][64];
    const int tid = threadIdx.x;
    const int n0 = blockIdx.x * 8;
    for (int i = tid; i < 512; i += 256)
        xs[i >> 6][i & 63] = x[(size_t)(n0 + (i >> 6)) * 64 + (i & 63)];
    __syncthreads();
    const int q = tid >> 6, c = tid & 63;
    const float* __restrict__ wp = ((q & 2) ? wsp : wf) + ((q & 1) ? 64 * 64 : 0) + c;
    const float bias = (q == 0) ? bfp[c] : (q == 2 ? bsp[c] : 0.f);
    float acc[8];
    #pragma unroll
    for (int g = 0; g < 8; ++g) acc[g] = bias;
    for (int k = 0; k < 64; ++k) {
        const float wv = wp[k * 64];
        #pragma unroll
        for (int g = 0; g < 8; ++g) acc[g] = fmaf(xs[g][k], wv, acc[g]);
    }
    if (q == 3) {
        #pragma unroll
        for (int g = 0; g < 8; ++g) sS[g][c] = acc[g];
    }
    __syncthreads();
    #pragma unroll
    for (int g = 0; g < 8; ++g) {
        const size_t n = n0 + g;
        if (q == 0)      Pi[n * 128 + c]      = acc[g];
        else if (q == 2) Pi[n * 128 + 64 + c] = acc[g];
        else if (q == 1) Pj16[n * 64 + c]     = __floats2half2_rn(acc[g], sS[g][c]);
    }
}

// ---------------- edge-parallel row-range conv: 8 rows/block, wave=edge ----------------
__launch_bounds__(256, 8)
__global__ void k_edge_range(const __half2* __restrict__ Pj,
                             const float* __restrict__ Pi,
                             const int2* __restrict__ rcP, const float4* __restrict__ ewP,
                             const float* __restrict__ wfe, const float* __restrict__ wse,
                             const int* __restrict__ rs,
                             const float* __restrict__ xin, float* __restrict__ out) {
    __shared__ float piS[8][128];         // staged row-side projections (4 KB)
    __shared__ float accS[4][8][64];      // per-wave accumulators (8 KB)
    __shared__ int rsS[9];
    const int tid = threadIdx.x;
    const int c = tid & 63, wv = tid >> 6;
    const int r0 = blockIdx.x * 8;
    for (int i = tid; i < 1024; i += 256)
        piS[i >> 7][i & 127] = Pi[(size_t)r0 * 128 + i];
    for (int i = tid; i < 2048; i += 256)
        ((float*)accS)[i] = 0.f;
    if (tid < 9) rsS[tid] = rs[r0 + tid];
    __syncthreads();
    const float wf0 = wfe[c], wf1 = wfe[64 + c], wf2 = wfe[128 + c];
    const float ws0 = wse[c], ws1 = wse[64 + c], ws2 = wse[128 + c];
    const int pbeg = rsS[0], pend = rsS[8];
    #pragma unroll 2
    for (int p = pbeg + wv; p < pend; p += 4) {
        const int2 rc = rcP[p];
        const float4 e = ewP[p];
        const float2 J = __half22float2(Pj[(size_t)rc.y * 64 + c]);
        const int row = rc.x - r0;
        const float af = piS[row][c]      + J.x + e.x * wf0 + e.y * wf1 + e.z * wf2;
        const float as = piS[row][64 + c] + J.y + e.x * ws0 + e.y * ws1 + e.z * ws2;
        const float sg = 1.f / (1.f + __expf(-af));
        const float sp = (as > 20.f) ? as : __logf(1.f + __expf(as));
        accS[wv][row][c] += sg * sp;
    }
    __syncthreads();
    for (int i = tid; i < 512; i += 256) {
        const int row = i >> 6, ch = i & 63;
        const float s = accS[0][row][ch] + accS[1][row][ch]
                      + accS[2][row][ch] + accS[3][row][ch];
        const int deg = rsS[row + 1] - rsS[row];
        const size_t o = (size_t)(r0 + row) * 64 + ch;
        out[o] = fmaxf(fmaf(s, 1.f / (float)max(deg, 1), xin[o]), 0.f);
    }
}

// ---------------- fused GRU: h = GRU(m, h), weights from L2 ----------------
__global__ void k_gru_fused(const float* __restrict__ m, float* __restrict__ h,
                            const float* __restrict__ wih, const float* __restrict__ bih,
                            const float* __restrict__ whh, const float* __restrict__ bhh) {
    __shared__ float ms[32 * 65], hs[32 * 65];
    const int tid = threadIdx.x;
    const int n0 = blockIdx.x * 32;
    for (int i = tid; i < 2048; i += 256) {
        ms[(i >> 6) * 65 + (i & 63)] = m[(size_t)n0 * 64 + i];
        hs[(i >> 6) * 65 + (i & 63)] = h[(size_t)n0 * 64 + i];
    }
    __syncthreads();
    const int c = tid & 63, tg = tid >> 6;
    float ir[8], iz[8], inn[8], hr[8], hz[8], hn[8];
    #pragma unroll
    for (int j = 0; j < 8; ++j) { ir[j]=0.f; iz[j]=0.f; inn[j]=0.f; hr[j]=0.f; hz[j]=0.f; hn[j]=0.f; }
    for (int k = 0; k < 64; ++k) {
        const float wir = wih[k * 192 + c];
        const float wiz = wih[k * 192 + 64 + c];
        const float win = wih[k * 192 + 128 + c];
        const float whr = whh[k * 192 + c];
        const float whz = whh[k * 192 + 64 + c];
        const float whn = whh[k * 192 + 128 + c];
        #pragma unroll
        for (int j = 0; j < 8; ++j) {
            const float mk = ms[(j * 4 + tg) * 65 + k];
            const float hk = hs[(j * 4 + tg) * 65 + k];
            ir[j]  = fmaf(mk, wir, ir[j]);
            iz[j]  = fmaf(mk, wiz, iz[j]);
            inn[j] = fmaf(mk, win, inn[j]);
            hr[j]  = fmaf(hk, whr, hr[j]);
            hz[j]  = fmaf(hk, whz, hz[j]);
            hn[j]  = fmaf(hk, whn, hn[j]);
        }
    }
    const float bir = bih[c], biz = bih[64 + c], bin = bih[128 + c];
    const float bhr = bhh[c], bhz = bhh[64 + c], bhn = bhh[128 + c];
    #pragma unroll
    for (int j = 0; j < 8; ++j) {
        const int n = n0 + j * 4 + tg;
        const float r  = 1.f / (1.f + __expf(-((ir[j] + bir) + (hr[j] + bhr))));
        const float zg = 1.f / (1.f + __expf(-((iz[j] + biz) + (hz[j] + bhz))));
        const float ng = tanhf((inn[j] + bin) + r * (hn[j] + bhn));
        h[(size_t)n * 64 + c] = (1.f - zg) * ng + zg * hs[(j * 4 + tg) * 65 + c];
    }
}

// ---------------- first-node-per-graph indices (searchsorted) ----------------
__global__ void k_idx(const int* __restrict__ batch, int* __restrict__ idx) {
    int g = threadIdx.x;
    if (g >= NGRAPH) return;
    int lo = 0, hi = NN;
    while (lo < hi) {
        int mid = (lo + hi) >> 1;
        if (batch[mid] < g) lo = mid + 1; else hi = mid;
    }
    idx[g] = lo;
}

// ---------------- readout head: all weights/activations in LDS ----------------
__global__ void k_head(const float* __restrict__ h, const int* __restrict__ idx,
                       const float* __restrict__ fcsw, const float* __restrict__ fcsb,
                       const float* __restrict__ f2cw, const float* __restrict__ f2cb,
                       const float* __restrict__ f3cw, const float* __restrict__ f3cb,
                       const float* __restrict__ f2dw, const float* __restrict__ f2db,
                       const float* __restrict__ f3dw, const float* __restrict__ f3db,
                       float* __restrict__ out) {
    __shared__ float hsB[4096];  // hsel -> xgs
    __shared__ float waB[4096];  // fcsw -> xcs
    __shared__ float wbB[4096];  // f2cw -> xds
    __shared__ float wcB[4096];  // f2dw -> f3 weights
    const int tid = threadIdx.x;
    for (int i = tid; i < 4096; i += 256) {
        int g = i >> 6, k = i & 63;
        hsB[i] = h[(size_t)idx[g] * 64 + k];
        waB[i] = fcsw[i];
        wbB[i] = f2cw[i];
        wcB[i] = f2dw[i];
    }
    __syncthreads();
    float v[16];
    #pragma unroll
    for (int j = 0; j < 16; ++j) {
        const int i = j * 256 + tid, g = i >> 6, c = i & 63;
        float a = fcsb[c];
        for (int k = 0; k < 64; ++k) a = fmaf(hsB[g * 64 + k], waB[k * 64 + c], a);
        v[j] = fmaxf(a, 0.f);
    }
    __syncthreads();
    #pragma unroll
    for (int j = 0; j < 16; ++j) hsB[j * 256 + tid] = v[j];   // xgs
    __syncthreads();
    float vc[16], vd[16];
    #pragma unroll
    for (int j = 0; j < 16; ++j) {
        const int i = j * 256 + tid, g = i >> 6, c = i & 63;
        float a1 = f2cb[c], a2 = f2db[c];
        for (int k = 0; k < 64; ++k) {
            const float xv = hsB[g * 64 + k];
            a1 = fmaf(xv, wbB[k * 64 + c], a1);
            a2 = fmaf(xv, wcB[k * 64 + c], a2);
        }
        vc[j] = fmaxf(a1, 0.f);
        vd[j] = fmaxf(a2, 0.f);
    }
    __syncthreads();
    #pragma unroll
    for (int j = 0; j < 16; ++j) {
        waB[j * 256 + tid] = vc[j];   // xcs
        wbB[j * 256 + tid] = vd[j];   // xds
    }
    if (tid < 128) wcB[tid] = f3cw[tid];
    else           wcB[tid] = f3dw[tid - 128];
    __syncthreads();
    if (tid < 128) {
        int g = tid >> 1, j = tid & 1;
        float a = f3cb[j];
        for (int k = 0; k < 64; ++k) a = fmaf(waB[g * 64 + k], wcB[k * 2 + j], a);
        out[g * 2 + j] = 1.f / (1.f + expf(-a));
    } else {
        int t = tid - 128, g = t >> 1, j = t & 1;
        float a = f3db[j];
        for (int k = 0; k < 64; ++k) a = fmaf(wbB[g * 64 + k], wcB[128 + k * 2 + j], a);
        out[128 + g * 2 + j] = a;
    }
}

// ---------------- host launcher ----------------
extern "C" void kernel_launch(void* const* d_in, const int* in_sizes, int n_in,
                              void* d_out, int out_size, void* d_ws, size_t ws_size,
                              hipStream_t stream) {
    (void)in_sizes; (void)n_in; (void)out_size; (void)ws_size;
    const float* x    = (const float*)d_in[0];
    const int* ei1    = (const int*)d_in[1];
    const int* ei2    = (const int*)d_in[2];
    const float* w1   = (const float*)d_in[3];
    const float* w2   = (const float*)d_in[4];
    const int* batch  = (const int*)d_in[5];
    const float* fc1w = (const float*)d_in[6];
    const float* fc1b = (const float*)d_in[7];
    const float* lfw  = (const float*)d_in[8];
    const float* lfb  = (const float*)d_in[9];
    const float* lsw  = (const float*)d_in[10];
    const float* lsb  = (const float*)d_in[11];
    const float* wih  = (const float*)d_in[12];
    const float* bih  = (const float*)d_in[13];
    const float* whh  = (const float*)d_in[14];
    const float* bhh  = (const float*)d_in[15];
    const float* fcsw = (const float*)d_in[16];
    const float* fcsb = (const float*)d_in[17];
    const float* f2cw = (const float*)d_in[18];
    const float* f2cb = (const float*)d_in[19];
    const float* f3cw = (const float*)d_in[20];
    const float* f3cb = (const float*)d_in[21];
    const float* f2dw = (const float*)d_in[22];
    const float* f2db = (const float*)d_in[23];
    const float* f3dw = (const float*)d_in[24];
    const float* f3db = (const float*)d_in[25];

    char* ws = (char*)d_ws;
    size_t off = 0;
    auto alloc = [&](size_t bytes) { char* p = ws + off; off += (bytes + 255) & ~size_t(255); return p; };
    float*   Pi    = (float*)alloc(size_t(NN) * 128 * 4);      // 20.5 MB
    __half2* Pj16  = (__half2*)alloc(size_t(NN) * 64 * 4);     // 10.2 MB
    float*   hbuf  = (float*)alloc(size_t(NN) * CD * 4);
    float*   mbuf  = (float*)alloc(size_t(NN) * CD * 4);
    int*   cnt1  = (int*)alloc(size_t(NN) * 4);
    int*   cnt2  = (int*)alloc(size_t(NN) * 4);
    int*   rs1   = (int*)alloc(size_t(NN + 1) * 4);
    int*   rs2   = (int*)alloc(size_t(NN + 1) * 4);
    int*   cur1  = (int*)alloc(size_t(NN + 1) * 4);
    int*   cur2  = (int*)alloc(size_t(NN + 1) * 4);
    int*   perm1 = (int*)alloc(size_t(NE) * 4);
    int*   perm2 = (int*)alloc(size_t(NE) * 4);
    int2*  rcP1  = (int2*)alloc(size_t(NE) * 8);
    int2*  rcP2  = (int2*)alloc(size_t(NE) * 8);
    float4* ewP1 = (float4*)alloc(size_t(NE) * 16);
    float4* ewP2 = (float4*)alloc(size_t(NE) * 16);
    int*   part1 = (int*)alloc(256 * 4);
    int*   part2 = (int*)alloc(256 * 4);
    int*   offs1 = (int*)alloc(256 * 4);
    int*   offs2 = (int*)alloc(256 * 4);
    int*   idx   = (int*)alloc(256);

    const int NB_NC = (NN * CD + 255) / 256;
    const int NB_E  = (NE + 255) / 256;
    const int EDGE_BLOCKS = NN / 8;    // 5000 row-range blocks
    const int PROJ_BLOCKS = NN / 8;    // 5000
    const int GRU_BLOCKS  = NN / 32;   // 1250

    const float* lfe = lfw + 128 * 64;
    const float* lse = lsw + 128 * 64;

    // CSR build (parallel scan) + packed edge pre-gather
    hipMemsetAsync(cnt1, 0, size_t(NN) * 4, stream);
    hipMemsetAsync(cnt2, 0, size_t(NN) * 4, stream);
    k_count<<<NB_E, 256, 0, stream>>>(ei1, cnt1);
    k_count<<<NB_E, 256, 0, stream>>>(ei2, cnt2);
    k_scan_part<<<SCAN_BLOCKS, 256, 0, stream>>>(cnt1, part1);
    k_scan_part<<<SCAN_BLOCKS, 256, 0, stream>>>(cnt2, part2);
    k_scan_mid<<<1, 256, 0, stream>>>(part1, offs1, SCAN_BLOCKS);
    k_scan_mid<<<1, 256, 0, stream>>>(part2, offs2, SCAN_BLOCKS);
    k_scan_fill<<<SCAN_BLOCKS, 256, 0, stream>>>(cnt1, offs1, rs1, cur1);
    k_scan_fill<<<SCAN_BLOCKS, 256, 0, stream>>>(cnt2, offs2, rs2, cur2);
    k_scatter<<<NB_E, 256, 0, stream>>>(ei1, cur1, perm1);
    k_scatter<<<NB_E, 256, 0, stream>>>(ei2, cur2, perm2);
    k_edge_gather<<<NB_E, 256, 0, stream>>>(ei1, w1, perm1, rcP1, ewP1);
    k_edge_gather<<<NB_E, 256, 0, stream>>>(ei2, w2, perm2, rcP2, ewP2);

    k_fc1<<<NB_NC, 256, 0, stream>>>(x, fc1w, fc1b, hbuf);

    for (int it = 0; it < 3; ++it) {
        k_proj<<<PROJ_BLOCKS, 256, 0, stream>>>(hbuf, lfw, lfb, lsw, lsb, Pi, Pj16);
        k_edge_range<<<EDGE_BLOCKS, 256, 0, stream>>>(Pj16, Pi, rcP2, ewP2,
                                                      lfe, lse, rs2, hbuf, mbuf);
        k_proj<<<PROJ_BLOCKS, 256, 0, stream>>>(mbuf, lfw, lfb, lsw, lsb, Pi, Pj16);
        k_edge_range<<<EDGE_BLOCKS, 256, 0, stream>>>(Pj16, Pi, rcP1, ewP1,
                                                      lfe, lse, rs1, mbuf, mbuf);
        k_gru_fused<<<GRU_BLOCKS, 256, 0, stream>>>(mbuf, hbuf, wih, bih, whh, bhh);
    }

    k_idx<<<1, 64, 0, stream>>>(batch, idx);
    k_head<<<1, 256, 0, stream>>>(hbuf, idx, fcsw, fcsb, f2cw, f2cb, f3cw, f3cb,
                                  f2dw, f2db, f3dw, f3db, (float*)d_out);
}